// Round 1
// baseline (454.215 us; speedup 1.0000x reference)
//
#include <hip/hip_runtime.h>

#define DD 128
#define AA 64

static inline int idiv_up(int a, int b) { return (a + b - 1) / b; }

// out[i][a] = dot(src[row(i)][:], W[:][a]) + bias[a]
// row(i) = idx ? idx[i] : i.  Block: 256 threads = 4 rows x 64 outputs.
__global__ void rowmm_kernel(const float* __restrict__ src,
                             const float* __restrict__ W,
                             const float* __restrict__ bias,
                             const int* __restrict__ idx,
                             float* __restrict__ out, int nrows) {
    __shared__ float lds[4][DD];
    const int t = threadIdx.x;
    const int rl = t >> 6;        // local row 0..3
    const int a = t & 63;         // output col 0..63
    const int i = blockIdx.x * 4 + rl;
    if (i < nrows) {
        const int row = idx ? idx[i] : i;
        const float* srow = src + (long)row * DD;
        lds[rl][a]      = srow[a];
        lds[rl][a + 64] = srow[a + 64];
    }
    __syncthreads();
    if (i >= nrows) return;
    float acc = bias ? bias[a] : 0.0f;
    #pragma unroll 8
    for (int d = 0; d < DD; ++d)
        acc = fmaf(lds[rl][d], W[d * AA + a], acc);
    out[(long)i * AA + a] = acc;
}

// One wave per edge (grid-stride). Gather precomputed projections, wave-reduce
// the attention logit, sigmoid, scatter alpha*(hs+hr) with HW fp32 atomics.
__global__ void edge_kernel(const int* __restrict__ edges,
                            const float* __restrict__ hsWs,
                            const float* __restrict__ hrWr,
                            const float* __restrict__ hqrWqr,
                            const float* __restrict__ hidden,
                            const float* __restrict__ rela,
                            const float* __restrict__ wa,
                            const float* __restrict__ ba,
                            float* agg, int E) {
    const int lane = threadIdx.x & 63;
    const int wid  = (int)((blockIdx.x * blockDim.x + threadIdx.x) >> 6);
    const int nw   = (int)((gridDim.x * blockDim.x) >> 6);
    const float war = wa[lane];
    const float bar = ba[0];
    for (int e = wid; e < E; e += nw) {
        const int* ed = edges + (long)e * 6;
        const int ridx = ed[0];
        const int rel  = ed[2];
        const int sub  = ed[4];
        const int obj  = ed[5];
        float pre = hsWs[(long)sub * 64 + lane]
                  + hrWr[(long)rel * 64 + lane]
                  + hqrWqr[(long)ridx * 64 + lane];
        float p = fmaxf(pre, 0.0f) * war;
        #pragma unroll
        for (int o = 32; o > 0; o >>= 1) p += __shfl_xor(p, o, 64);
        const float alpha = 1.0f / (1.0f + __expf(-(p + bar)));
        const float* hsrow = hidden + (long)sub * DD;
        const float* hrrow = rela   + (long)rel * DD;
        const float m0 = alpha * (hsrow[lane]      + hrrow[lane]);
        const float m1 = alpha * (hsrow[lane + 64] + hrrow[lane + 64]);
        float* arow = agg + (long)obj * DD;
        unsafeAtomicAdd(arow + lane,      m0);
        unsafeAtomicAdd(arow + lane + 64, m1);
    }
}

// out[64 rows x 128] = agg[64 rows x 128] @ Wh[128 x 128].
// In-place safe: each block stages ALL its agg rows into LDS (both d-chunks)
// before any store, and no other block touches these rows.
__global__ void out_gemm_kernel(const float* agg,
                                const float* __restrict__ Wh,
                                float* out, int nrows) {
    __shared__ float whs[64 * 128];   // Wh rows dc..dc+64
    __shared__ float ags[64 * 64];    // agg tile rows x d-chunk
    const int t = threadIdx.x;
    const int rbase = blockIdx.x * 64;
    const int j0 = (t & 31) * 4;      // output col
    const int rh = t >> 5;            // 0..7
    const int r0 = rh * 8;            // 8 rows per thread
    float acc[8][4];
    #pragma unroll
    for (int r = 0; r < 8; ++r)
        #pragma unroll
        for (int j = 0; j < 4; ++j) acc[r][j] = 0.0f;

    for (int dc = 0; dc < 128; dc += 64) {
        #pragma unroll
        for (int k = 0; k < 8192; k += 1024) {
            const int f = k + t * 4;
            *(float4*)&whs[f] = *(const float4*)&Wh[(long)dc * 128 + f];
        }
        #pragma unroll
        for (int k = 0; k < 4096; k += 1024) {
            const int f = k + t * 4;
            const int r = f >> 6;
            const int c = f & 63;
            float4 v = make_float4(0.0f, 0.0f, 0.0f, 0.0f);
            if (rbase + r < nrows)
                v = *(const float4*)&agg[(long)(rbase + r) * 128 + dc + c];
            *(float4*)&ags[f] = v;
        }
        __syncthreads();
        for (int d = 0; d < 64; d += 4) {
            const float4 wv0 = *(const float4*)&whs[(d + 0) * 128 + j0];
            const float4 wv1 = *(const float4*)&whs[(d + 1) * 128 + j0];
            const float4 wv2 = *(const float4*)&whs[(d + 2) * 128 + j0];
            const float4 wv3 = *(const float4*)&whs[(d + 3) * 128 + j0];
            #pragma unroll
            for (int r = 0; r < 8; ++r) {
                const float4 av = *(const float4*)&ags[(r0 + r) * 64 + d];
                acc[r][0] = fmaf(av.x, wv0.x, acc[r][0]);
                acc[r][1] = fmaf(av.x, wv0.y, acc[r][1]);
                acc[r][2] = fmaf(av.x, wv0.z, acc[r][2]);
                acc[r][3] = fmaf(av.x, wv0.w, acc[r][3]);
                acc[r][0] = fmaf(av.y, wv1.x, acc[r][0]);
                acc[r][1] = fmaf(av.y, wv1.y, acc[r][1]);
                acc[r][2] = fmaf(av.y, wv1.z, acc[r][2]);
                acc[r][3] = fmaf(av.y, wv1.w, acc[r][3]);
                acc[r][0] = fmaf(av.z, wv2.x, acc[r][0]);
                acc[r][1] = fmaf(av.z, wv2.y, acc[r][1]);
                acc[r][2] = fmaf(av.z, wv2.z, acc[r][2]);
                acc[r][3] = fmaf(av.z, wv2.w, acc[r][3]);
                acc[r][0] = fmaf(av.w, wv3.x, acc[r][0]);
                acc[r][1] = fmaf(av.w, wv3.y, acc[r][1]);
                acc[r][2] = fmaf(av.w, wv3.z, acc[r][2]);
                acc[r][3] = fmaf(av.w, wv3.w, acc[r][3]);
            }
        }
        __syncthreads();
    }
    #pragma unroll
    for (int r = 0; r < 8; ++r) {
        const int row = rbase + r0 + r;
        if (row < nrows)
            *(float4*)&out[(long)row * 128 + j0] =
                make_float4(acc[r][0], acc[r][1], acc[r][2], acc[r][3]);
    }
}

extern "C" void kernel_launch(void* const* d_in, const int* in_sizes, int n_in,
                              void* d_out, int out_size, void* d_ws, size_t ws_size,
                              hipStream_t stream) {
    // inputs: 0 q_sub (unused), 1 q_rel, 2 hidden, 3 edges, 4 n_node,
    //         5 rela_embed, 6 Ws, 7 Wr, 8 Wqr, 9 bqr, 10 wa, 11 ba, 12 Wh
    const int*   q_rel  = (const int*)d_in[1];
    const float* hidden = (const float*)d_in[2];
    const int*   edges  = (const int*)d_in[3];
    const float* rela   = (const float*)d_in[5];
    const float* Ws     = (const float*)d_in[6];
    const float* Wr     = (const float*)d_in[7];
    const float* Wqr    = (const float*)d_in[8];
    const float* bqr    = (const float*)d_in[9];
    const float* wa     = (const float*)d_in[10];
    const float* ba     = (const float*)d_in[11];
    const float* Wh     = (const float*)d_in[12];

    const int B  = in_sizes[1];
    const int N  = in_sizes[2] / DD;
    const int E  = in_sizes[3] / 6;
    const int NR = in_sizes[5] / DD;

    float* out = (float*)d_out;
    float* hsWs   = (float*)d_ws;                   // N  x 64
    float* hrWr   = hsWs   + (size_t)N  * AA;       // NR x 64
    float* hqrWqr = hrWr   + (size_t)NR * AA;       // B  x 64 (bqr folded in)
    float* agg    = out;                            // N x 128 accumulator lives in d_out

    hipMemsetAsync(agg, 0, (size_t)N * DD * sizeof(float), stream);
    rowmm_kernel<<<idiv_up(N, 4),  256, 0, stream>>>(hidden, Ws,  nullptr, nullptr, hsWs,   N);
    rowmm_kernel<<<idiv_up(NR, 4), 256, 0, stream>>>(rela,   Wr,  nullptr, nullptr, hrWr,   NR);
    rowmm_kernel<<<idiv_up(B, 4),  256, 0, stream>>>(rela,   Wqr, bqr,     q_rel,   hqrWqr, B);
    edge_kernel<<<2048, 256, 0, stream>>>(edges, hsWs, hrWr, hqrWqr, hidden, rela,
                                          wa, ba, agg, E);
    out_gemm_kernel<<<idiv_up(N, 64), 256, 0, stream>>>(agg, Wh, out, N);
}

// Round 2
// 332.406 us; speedup vs baseline: 1.3664x; 1.3664x over previous
//
#include <hip/hip_runtime.h>

#define DD 128
#define AA 64

static inline int idiv_up(int a, int b) { return (a + b - 1) / b; }

// ---------- small projection (401 and 100 rows): simple per-row kernel ----------
__global__ void rowmm_kernel(const float* __restrict__ src,
                             const float* __restrict__ W,
                             const float* __restrict__ bias,
                             const int* __restrict__ idx,
                             float* __restrict__ out, int nrows) {
    __shared__ float lds[4][DD];
    const int t = threadIdx.x;
    const int rl = t >> 6;
    const int a = t & 63;
    const int i = blockIdx.x * 4 + rl;
    if (i < nrows) {
        const int row = idx ? idx[i] : i;
        const float* srow = src + (long)row * DD;
        lds[rl][a]      = srow[a];
        lds[rl][a + 64] = srow[a + 64];
    }
    __syncthreads();
    if (i >= nrows) return;
    float acc = bias ? bias[a] : 0.0f;
    #pragma unroll 8
    for (int d = 0; d < DD; ++d)
        acc = fmaf(lds[rl][d], W[d * AA + a], acc);
    out[(long)i * AA + a] = acc;
}

// ---------- big projection: hsWs[N][64] = hidden[N][128] @ Ws[128][64] ----------
// 64-row tile, transposed-hidden LDS staging, 2x ds_read_b128 per 16 FMA.
__global__ void proj_gemm_kernel(const float* __restrict__ src,
                                 const float* __restrict__ W,
                                 float* __restrict__ out, int nrows) {
    __shared__ float lw[128 * 64];    // [d][c]
    __shared__ float lht[128 * 64];   // transposed: [d][row]
    const int t = threadIdx.x;
    const int rbase = blockIdx.x * 64;
    #pragma unroll
    for (int k = 0; k < 8192; k += 1024)
        *(float4*)&lw[k + t * 4] = *(const float4*)&W[k + t * 4];
    const int row = t & 63;
    const int d0 = (t >> 6) * 32;
    const int gr = rbase + row;
    #pragma unroll
    for (int j = 0; j < 8; ++j) {
        float4 v = make_float4(0.f, 0.f, 0.f, 0.f);
        if (gr < nrows) v = *(const float4*)&src[(long)gr * 128 + d0 + j * 4];
        lht[(d0 + j * 4 + 0) * 64 + row] = v.x;
        lht[(d0 + j * 4 + 1) * 64 + row] = v.y;
        lht[(d0 + j * 4 + 2) * 64 + row] = v.z;
        lht[(d0 + j * 4 + 3) * 64 + row] = v.w;
    }
    __syncthreads();
    const int r0 = (t & 15) * 4;
    const int c0 = (t >> 4) * 4;
    float acc[4][4] = {};
    #pragma unroll 4
    for (int d = 0; d < 128; ++d) {
        const float4 hv = *(const float4*)&lht[d * 64 + r0];
        const float4 wv = *(const float4*)&lw[d * 64 + c0];
        acc[0][0] = fmaf(hv.x, wv.x, acc[0][0]);
        acc[0][1] = fmaf(hv.x, wv.y, acc[0][1]);
        acc[0][2] = fmaf(hv.x, wv.z, acc[0][2]);
        acc[0][3] = fmaf(hv.x, wv.w, acc[0][3]);
        acc[1][0] = fmaf(hv.y, wv.x, acc[1][0]);
        acc[1][1] = fmaf(hv.y, wv.y, acc[1][1]);
        acc[1][2] = fmaf(hv.y, wv.z, acc[1][2]);
        acc[1][3] = fmaf(hv.y, wv.w, acc[1][3]);
        acc[2][0] = fmaf(hv.z, wv.x, acc[2][0]);
        acc[2][1] = fmaf(hv.z, wv.y, acc[2][1]);
        acc[2][2] = fmaf(hv.z, wv.z, acc[2][2]);
        acc[2][3] = fmaf(hv.z, wv.w, acc[2][3]);
        acc[3][0] = fmaf(hv.w, wv.x, acc[3][0]);
        acc[3][1] = fmaf(hv.w, wv.y, acc[3][1]);
        acc[3][2] = fmaf(hv.w, wv.z, acc[3][2]);
        acc[3][3] = fmaf(hv.w, wv.w, acc[3][3]);
    }
    #pragma unroll
    for (int i = 0; i < 4; ++i) {
        const int orow = rbase + r0 + i;
        if (orow < nrows)
            *(float4*)&out[(long)orow * 64 + c0] =
                make_float4(acc[i][0], acc[i][1], acc[i][2], acc[i][3]);
    }
}

// ---------- counting sort by obj ----------
__global__ void hist_kernel(const int* __restrict__ edges, int* deg, int E) {
    const int e = blockIdx.x * blockDim.x + threadIdx.x;
    if (e < E) atomicAdd(&deg[edges[(long)e * 6 + 5]], 1);
}

// exclusive scan, 1024 elems/block (256 threads x 4)
__global__ void scan1_kernel(const int* __restrict__ in, int* __restrict__ out,
                             int* __restrict__ bsum, int n) {
    __shared__ int tsum[256];
    const int t = threadIdx.x;
    const int base = blockIdx.x * 1024 + t * 4;
    int v[4];
    int s = 0;
    #pragma unroll
    for (int j = 0; j < 4; ++j) {
        v[j] = (base + j < n) ? in[base + j] : 0;
        s += v[j];
    }
    tsum[t] = s;
    __syncthreads();
    for (int o = 1; o < 256; o <<= 1) {
        int x = (t >= o) ? tsum[t - o] : 0;
        __syncthreads();
        tsum[t] += x;
        __syncthreads();
    }
    int run = (t > 0) ? tsum[t - 1] : 0;
    if (t == 255 && bsum) bsum[blockIdx.x] = tsum[255];
    #pragma unroll
    for (int j = 0; j < 4; ++j) {
        if (base + j < n) out[base + j] = run;
        run += v[j];
    }
}

__global__ void scan_add_kernel(int* out, const int* __restrict__ bsumx, int n) {
    const int i = blockIdx.x * blockDim.x + threadIdx.x;
    if (i < n) out[i] += bsumx[i >> 10];
}

// pack (sub, rel | ridx<<16) records bucketed by obj
__global__ void scatter_kernel(const int* __restrict__ edges,
                               const int* __restrict__ offs, int* cur,
                               int2* __restrict__ recs, int E) {
    const int e = blockIdx.x * blockDim.x + threadIdx.x;
    if (e >= E) return;
    const int* ed = edges + (long)e * 6;
    const int obj = ed[5];
    const int pos = offs[obj] + atomicAdd(&cur[obj], 1);
    recs[pos] = make_int2(ed[4], ed[2] | (ed[0] << 16));
}

// ---------- one wave per destination node: alpha inline + register accumulate ----------
__global__ void gather_kernel(const int2* __restrict__ recs,
                              const int* __restrict__ offs,
                              const float* __restrict__ hsWs,
                              const float* __restrict__ hrWr,
                              const float* __restrict__ hqrWqr,
                              const float* __restrict__ hidden,
                              const float* __restrict__ rela,
                              const float* __restrict__ wa,
                              const float* __restrict__ ba,
                              float* __restrict__ agg, int N, int E) {
    const int lane = threadIdx.x & 63;
    const int v = (int)((blockIdx.x * blockDim.x + threadIdx.x) >> 6);
    if (v >= N) return;
    const float war = wa[lane];
    const float bar = ba[0];
    const int start = offs[v];
    const int end = (v + 1 < N) ? offs[v + 1] : E;
    float acc0 = 0.0f, acc1 = 0.0f;
    for (int k = start; k < end; ++k) {
        const int2 rec = recs[k];
        const int sub  = rec.x;
        const int rel  = rec.y & 0xffff;
        const int ridx = rec.y >> 16;
        float pre = hsWs[(long)sub * 64 + lane]
                  + hrWr[rel * 64 + lane]
                  + hqrWqr[ridx * 64 + lane];
        float p = fmaxf(pre, 0.0f) * war;
        #pragma unroll
        for (int o = 32; o > 0; o >>= 1) p += __shfl_xor(p, o, 64);
        const float alpha = 1.0f / (1.0f + expf(-(p + bar)));
        acc0 = fmaf(alpha, hidden[(long)sub * DD + lane]      + rela[rel * DD + lane],      acc0);
        acc1 = fmaf(alpha, hidden[(long)sub * DD + 64 + lane] + rela[rel * DD + 64 + lane], acc1);
    }
    agg[(long)v * DD + lane]      = acc0;
    agg[(long)v * DD + 64 + lane] = acc1;
}

// ---------- out[64x128] = agg[64x128] @ Wh[128x128], in-place safe ----------
__global__ void out_gemm_kernel(const float* agg,
                                const float* __restrict__ Wh,
                                float* out, int nrows) {
    __shared__ float whs[64 * 128];
    __shared__ float ags[64 * 64];
    const int t = threadIdx.x;
    const int rbase = blockIdx.x * 64;
    const int j0 = (t & 31) * 4;
    const int rh = t >> 5;
    const int r0 = rh * 8;
    float acc[8][4];
    #pragma unroll
    for (int r = 0; r < 8; ++r)
        #pragma unroll
        for (int j = 0; j < 4; ++j) acc[r][j] = 0.0f;

    for (int dc = 0; dc < 128; dc += 64) {
        #pragma unroll
        for (int k = 0; k < 8192; k += 1024) {
            const int f = k + t * 4;
            *(float4*)&whs[f] = *(const float4*)&Wh[(long)dc * 128 + f];
        }
        #pragma unroll
        for (int k = 0; k < 4096; k += 1024) {
            const int f = k + t * 4;
            const int r = f >> 6;
            const int c = f & 63;
            float4 v = make_float4(0.0f, 0.0f, 0.0f, 0.0f);
            if (rbase + r < nrows)
                v = *(const float4*)&agg[(long)(rbase + r) * 128 + dc + c];
            *(float4*)&ags[f] = v;
        }
        __syncthreads();
        for (int d = 0; d < 64; d += 4) {
            const float4 wv0 = *(const float4*)&whs[(d + 0) * 128 + j0];
            const float4 wv1 = *(const float4*)&whs[(d + 1) * 128 + j0];
            const float4 wv2 = *(const float4*)&whs[(d + 2) * 128 + j0];
            const float4 wv3 = *(const float4*)&whs[(d + 3) * 128 + j0];
            #pragma unroll
            for (int r = 0; r < 8; ++r) {
                const float4 av = *(const float4*)&ags[(r0 + r) * 64 + d];
                acc[r][0] = fmaf(av.x, wv0.x, acc[r][0]);
                acc[r][1] = fmaf(av.x, wv0.y, acc[r][1]);
                acc[r][2] = fmaf(av.x, wv0.z, acc[r][2]);
                acc[r][3] = fmaf(av.x, wv0.w, acc[r][3]);
                acc[r][0] = fmaf(av.y, wv1.x, acc[r][0]);
                acc[r][1] = fmaf(av.y, wv1.y, acc[r][1]);
                acc[r][2] = fmaf(av.y, wv1.z, acc[r][2]);
                acc[r][3] = fmaf(av.y, wv1.w, acc[r][3]);
                acc[r][0] = fmaf(av.z, wv2.x, acc[r][0]);
                acc[r][1] = fmaf(av.z, wv2.y, acc[r][1]);
                acc[r][2] = fmaf(av.z, wv2.z, acc[r][2]);
                acc[r][3] = fmaf(av.z, wv2.w, acc[r][3]);
                acc[r][0] = fmaf(av.w, wv3.x, acc[r][0]);
                acc[r][1] = fmaf(av.w, wv3.y, acc[r][1]);
                acc[r][2] = fmaf(av.w, wv3.z, acc[r][2]);
                acc[r][3] = fmaf(av.w, wv3.w, acc[r][3]);
            }
        }
        __syncthreads();
    }
    #pragma unroll
    for (int r = 0; r < 8; ++r) {
        const int row = rbase + r0 + r;
        if (row < nrows)
            *(float4*)&out[(long)row * 128 + j0] =
                make_float4(acc[r][0], acc[r][1], acc[r][2], acc[r][3]);
    }
}

extern "C" void kernel_launch(void* const* d_in, const int* in_sizes, int n_in,
                              void* d_out, int out_size, void* d_ws, size_t ws_size,
                              hipStream_t stream) {
    // inputs: 0 q_sub (unused), 1 q_rel, 2 hidden, 3 edges, 4 n_node,
    //         5 rela_embed, 6 Ws, 7 Wr, 8 Wqr, 9 bqr, 10 wa, 11 ba, 12 Wh
    const int*   q_rel  = (const int*)d_in[1];
    const float* hidden = (const float*)d_in[2];
    const int*   edges  = (const int*)d_in[3];
    const float* rela   = (const float*)d_in[5];
    const float* Ws     = (const float*)d_in[6];
    const float* Wr     = (const float*)d_in[7];
    const float* Wqr    = (const float*)d_in[8];
    const float* bqr    = (const float*)d_in[9];
    const float* wa     = (const float*)d_in[10];
    const float* ba     = (const float*)d_in[11];
    const float* Wh     = (const float*)d_in[12];

    const int B  = in_sizes[1];
    const int N  = in_sizes[2] / DD;
    const int E  = in_sizes[3] / 6;
    const int NR = in_sizes[5] / DD;

    float* out = (float*)d_out;

    // workspace layout (all 4B types; int2 region is 8B-aligned by construction)
    float* hsWs   = (float*)d_ws;                    // N  x 64
    float* hrWr   = hsWs   + (size_t)N  * AA;        // NR x 64
    float* hqrWqr = hrWr   + (size_t)NR * AA;        // B  x 64
    int*   deg    = (int*)(hqrWqr + (size_t)B * AA); // N
    int*   cur    = deg  + N;                        // N
    int*   offs   = cur  + N;                        // N
    int*   bsum   = offs + N;                        // 64
    int*   bsumx  = bsum + 64;                       // 64
    int2*  recs   = (int2*)(bsumx + 64);             // E

    const int nb = idiv_up(N, 1024);

    hipMemsetAsync(deg, 0, (size_t)2 * N * sizeof(int), stream);  // deg + cur
    proj_gemm_kernel<<<idiv_up(N, 64), 256, 0, stream>>>(hidden, Ws, hsWs, N);
    rowmm_kernel<<<idiv_up(NR, 4), 256, 0, stream>>>(rela, Wr, nullptr, nullptr, hrWr, NR);
    rowmm_kernel<<<idiv_up(B, 4), 256, 0, stream>>>(rela, Wqr, bqr, q_rel, hqrWqr, B);
    hist_kernel<<<idiv_up(E, 256), 256, 0, stream>>>(edges, deg, E);
    scan1_kernel<<<nb, 256, 0, stream>>>(deg, offs, bsum, N);
    scan1_kernel<<<1, 256, 0, stream>>>(bsum, bsumx, nullptr, nb);
    scan_add_kernel<<<idiv_up(N, 256), 256, 0, stream>>>(offs, bsumx, N);
    scatter_kernel<<<idiv_up(E, 256), 256, 0, stream>>>(edges, offs, cur, recs, E);
    gather_kernel<<<idiv_up(N * 64, 256), 256, 0, stream>>>(recs, offs, hsWs, hrWr, hqrWqr,
                                                            hidden, rela, wa, ba, out, N, E);
    out_gemm_kernel<<<idiv_up(N, 64), 256, 0, stream>>>(out, Wh, out, N);
}

// Round 3
// 306.123 us; speedup vs baseline: 1.4838x; 1.0859x over previous
//
#include <hip/hip_runtime.h>

#define DD 128
#define AA 64

static inline int idiv_up(int a, int b) { return (a + b - 1) / b; }

// ---------- small projection (401 and 100 rows): simple per-row kernel ----------
__global__ void rowmm_kernel(const float* __restrict__ src,
                             const float* __restrict__ W,
                             const float* __restrict__ bias,
                             const int* __restrict__ idx,
                             float* __restrict__ out, int nrows) {
    __shared__ float lds[4][DD];
    const int t = threadIdx.x;
    const int rl = t >> 6;
    const int a = t & 63;
    const int i = blockIdx.x * 4 + rl;
    if (i < nrows) {
        const int row = idx ? idx[i] : i;
        const float* srow = src + (long)row * DD;
        lds[rl][a]      = srow[a];
        lds[rl][a + 64] = srow[a + 64];
    }
    __syncthreads();
    if (i >= nrows) return;
    float acc = bias ? bias[a] : 0.0f;
    #pragma unroll 8
    for (int d = 0; d < DD; ++d)
        acc = fmaf(lds[rl][d], W[d * AA + a], acc);
    out[(long)i * AA + a] = acc;
}

// ---------- big projection: hsWs[N][64] = hidden[N][128] @ Ws[128][64] ----------
__global__ void proj_gemm_kernel(const float* __restrict__ src,
                                 const float* __restrict__ W,
                                 float* __restrict__ out, int nrows) {
    __shared__ float lw[128 * 64];    // [d][c]
    __shared__ float lht[128 * 64];   // transposed: [d][row]
    const int t = threadIdx.x;
    const int rbase = blockIdx.x * 64;
    #pragma unroll
    for (int k = 0; k < 8192; k += 1024)
        *(float4*)&lw[k + t * 4] = *(const float4*)&W[k + t * 4];
    const int row = t & 63;
    const int d0 = (t >> 6) * 32;
    const int gr = rbase + row;
    #pragma unroll
    for (int j = 0; j < 8; ++j) {
        float4 v = make_float4(0.f, 0.f, 0.f, 0.f);
        if (gr < nrows) v = *(const float4*)&src[(long)gr * 128 + d0 + j * 4];
        lht[(d0 + j * 4 + 0) * 64 + row] = v.x;
        lht[(d0 + j * 4 + 1) * 64 + row] = v.y;
        lht[(d0 + j * 4 + 2) * 64 + row] = v.z;
        lht[(d0 + j * 4 + 3) * 64 + row] = v.w;
    }
    __syncthreads();
    const int r0 = (t & 15) * 4;
    const int c0 = (t >> 4) * 4;
    float acc[4][4] = {};
    #pragma unroll 4
    for (int d = 0; d < 128; ++d) {
        const float4 hv = *(const float4*)&lht[d * 64 + r0];
        const float4 wv = *(const float4*)&lw[d * 64 + c0];
        acc[0][0] = fmaf(hv.x, wv.x, acc[0][0]);
        acc[0][1] = fmaf(hv.x, wv.y, acc[0][1]);
        acc[0][2] = fmaf(hv.x, wv.z, acc[0][2]);
        acc[0][3] = fmaf(hv.x, wv.w, acc[0][3]);
        acc[1][0] = fmaf(hv.y, wv.x, acc[1][0]);
        acc[1][1] = fmaf(hv.y, wv.y, acc[1][1]);
        acc[1][2] = fmaf(hv.y, wv.z, acc[1][2]);
        acc[1][3] = fmaf(hv.y, wv.w, acc[1][3]);
        acc[2][0] = fmaf(hv.z, wv.x, acc[2][0]);
        acc[2][1] = fmaf(hv.z, wv.y, acc[2][1]);
        acc[2][2] = fmaf(hv.z, wv.z, acc[2][2]);
        acc[2][3] = fmaf(hv.z, wv.w, acc[2][3]);
        acc[3][0] = fmaf(hv.w, wv.x, acc[3][0]);
        acc[3][1] = fmaf(hv.w, wv.y, acc[3][1]);
        acc[3][2] = fmaf(hv.w, wv.z, acc[3][2]);
        acc[3][3] = fmaf(hv.w, wv.w, acc[3][3]);
    }
    #pragma unroll
    for (int i = 0; i < 4; ++i) {
        const int orow = rbase + r0 + i;
        if (orow < nrows)
            *(float4*)&out[(long)orow * 64 + c0] =
                make_float4(acc[i][0], acc[i][1], acc[i][2], acc[i][3]);
    }
}

// ---------- counting sort by obj ----------
__global__ void hist_kernel(const int* __restrict__ edges, int* deg, int E) {
    const int e = blockIdx.x * blockDim.x + threadIdx.x;
    if (e < E) atomicAdd(&deg[edges[(long)e * 6 + 5]], 1);
}

__global__ void scan1_kernel(const int* __restrict__ in, int* __restrict__ out,
                             int* __restrict__ bsum, int n) {
    __shared__ int tsum[256];
    const int t = threadIdx.x;
    const int base = blockIdx.x * 1024 + t * 4;
    int v[4];
    int s = 0;
    #pragma unroll
    for (int j = 0; j < 4; ++j) {
        v[j] = (base + j < n) ? in[base + j] : 0;
        s += v[j];
    }
    tsum[t] = s;
    __syncthreads();
    for (int o = 1; o < 256; o <<= 1) {
        int x = (t >= o) ? tsum[t - o] : 0;
        __syncthreads();
        tsum[t] += x;
        __syncthreads();
    }
    int run = (t > 0) ? tsum[t - 1] : 0;
    if (t == 255 && bsum) bsum[blockIdx.x] = tsum[255];
    #pragma unroll
    for (int j = 0; j < 4; ++j) {
        if (base + j < n) out[base + j] = run;
        run += v[j];
    }
}

// offs += block prefix; also materialize cur = offs copy for the scatter atomics
__global__ void scan_add_kernel(int* offs, int* cur, const int* __restrict__ bsumx, int n) {
    const int i = blockIdx.x * blockDim.x + threadIdx.x;
    if (i < n) {
        const int v = offs[i] + bsumx[i >> 10];
        offs[i] = v;
        cur[i] = v;
    }
}

// pack (sub, rel | ridx<<16) records bucketed by obj; cur pre-seeded with offs
__global__ void scatter_kernel(const int* __restrict__ edges, int* cur,
                               int2* __restrict__ recs, int E) {
    const int e = blockIdx.x * blockDim.x + threadIdx.x;
    if (e >= E) return;
    const int* ed = edges + (long)e * 6;
    const int pos = atomicAdd(&cur[ed[5]], 1);
    recs[pos] = make_int2(ed[4], ed[2] | (ed[0] << 16));
}

// ---------- gather: one wave per node, 16 lanes per edge (4 edges in flight) ----------
__global__ void gather_kernel(const int2* __restrict__ recs,
                              const int* __restrict__ offs,
                              const float* __restrict__ hsWs,
                              const float* __restrict__ hrWr,
                              const float* __restrict__ hqrWqr,
                              const float* __restrict__ hidden,
                              const float* __restrict__ rela,
                              const float* __restrict__ wa,
                              const float* __restrict__ ba,
                              float* __restrict__ agg, int N, int E) {
    const int lane = threadIdx.x & 63;
    const int g = lane >> 4;      // edge-group 0..3
    const int l = lane & 15;      // lane within group
    const int v = (int)((blockIdx.x * blockDim.x + threadIdx.x) >> 6);
    if (v >= N) return;
    const float4 wav = *(const float4*)&wa[l * 4];
    const float bar = ba[0];
    const int start = offs[v];
    const int end = (v + 1 < N) ? offs[v + 1] : E;

    float4 acc0 = make_float4(0.f, 0.f, 0.f, 0.f);
    float4 acc1 = make_float4(0.f, 0.f, 0.f, 0.f);

    for (int base = start; base < end; base += 4) {
        const int k = base + g;
        const bool valid = (k < end);
        const int2 rec = valid ? recs[k] : make_int2(0, 0);
        const int sub  = rec.x;
        const int rel  = rec.y & 0xffff;
        const int ridx = rec.y >> 16;

        // logit: 4 features per lane, 16 lanes per edge
        const float4 a4 = *(const float4*)&hsWs[sub * AA + l * 4];
        const float4 b4 = *(const float4*)&hrWr[rel * AA + l * 4];
        const float4 c4 = *(const float4*)&hqrWqr[ridx * AA + l * 4];
        float s = fmaxf(a4.x + b4.x + c4.x, 0.f) * wav.x;
        s = fmaf(fmaxf(a4.y + b4.y + c4.y, 0.f), wav.y, s);
        s = fmaf(fmaxf(a4.z + b4.z + c4.z, 0.f), wav.z, s);
        s = fmaf(fmaxf(a4.w + b4.w + c4.w, 0.f), wav.w, s);
        s += __shfl_xor(s, 1);
        s += __shfl_xor(s, 2);
        s += __shfl_xor(s, 4);
        s += __shfl_xor(s, 8);
        float alpha = __builtin_amdgcn_rcpf(1.0f + __expf(-(s + bar)));
        if (!valid) alpha = 0.0f;

        // message: 8 features per lane (d = l*8 .. l*8+7)
        const float4 h0 = *(const float4*)&hidden[(long)sub * DD + l * 8];
        const float4 h1 = *(const float4*)&hidden[(long)sub * DD + l * 8 + 4];
        const float4 r0 = *(const float4*)&rela[rel * DD + l * 8];
        const float4 r1 = *(const float4*)&rela[rel * DD + l * 8 + 4];
        acc0.x = fmaf(alpha, h0.x + r0.x, acc0.x);
        acc0.y = fmaf(alpha, h0.y + r0.y, acc0.y);
        acc0.z = fmaf(alpha, h0.z + r0.z, acc0.z);
        acc0.w = fmaf(alpha, h0.w + r0.w, acc0.w);
        acc1.x = fmaf(alpha, h1.x + r1.x, acc1.x);
        acc1.y = fmaf(alpha, h1.y + r1.y, acc1.y);
        acc1.z = fmaf(alpha, h1.z + r1.z, acc1.z);
        acc1.w = fmaf(alpha, h1.w + r1.w, acc1.w);
    }

    // combine the 4 groups (lanes l, l+16, l+32, l+48 hold the same d-slots)
    #pragma unroll
    for (int o = 16; o <= 32; o <<= 1) {
        acc0.x += __shfl_xor(acc0.x, o);
        acc0.y += __shfl_xor(acc0.y, o);
        acc0.z += __shfl_xor(acc0.z, o);
        acc0.w += __shfl_xor(acc0.w, o);
        acc1.x += __shfl_xor(acc1.x, o);
        acc1.y += __shfl_xor(acc1.y, o);
        acc1.z += __shfl_xor(acc1.z, o);
        acc1.w += __shfl_xor(acc1.w, o);
    }
    if (g == 0) {
        *(float4*)&agg[(long)v * DD + l * 8]     = acc0;
        *(float4*)&agg[(long)v * DD + l * 8 + 4] = acc1;
    }
}

// ---------- out[64x128] = agg[64x128] @ Wh[128x128], in-place safe ----------
__global__ void out_gemm_kernel(const float* agg,
                                const float* __restrict__ Wh,
                                float* out, int nrows) {
    __shared__ float whs[64 * 128];
    __shared__ float ags[64 * 64];
    const int t = threadIdx.x;
    const int rbase = blockIdx.x * 64;
    const int j0 = (t & 31) * 4;
    const int rh = t >> 5;
    const int r0 = rh * 8;
    float acc[8][4];
    #pragma unroll
    for (int r = 0; r < 8; ++r)
        #pragma unroll
        for (int j = 0; j < 4; ++j) acc[r][j] = 0.0f;

    for (int dc = 0; dc < 128; dc += 64) {
        #pragma unroll
        for (int k = 0; k < 8192; k += 1024) {
            const int f = k + t * 4;
            *(float4*)&whs[f] = *(const float4*)&Wh[(long)dc * 128 + f];
        }
        #pragma unroll
        for (int k = 0; k < 4096; k += 1024) {
            const int f = k + t * 4;
            const int r = f >> 6;
            const int c = f & 63;
            float4 v = make_float4(0.0f, 0.0f, 0.0f, 0.0f);
            if (rbase + r < nrows)
                v = *(const float4*)&agg[(long)(rbase + r) * 128 + dc + c];
            *(float4*)&ags[f] = v;
        }
        __syncthreads();
        for (int d = 0; d < 64; d += 4) {
            const float4 wv0 = *(const float4*)&whs[(d + 0) * 128 + j0];
            const float4 wv1 = *(const float4*)&whs[(d + 1) * 128 + j0];
            const float4 wv2 = *(const float4*)&whs[(d + 2) * 128 + j0];
            const float4 wv3 = *(const float4*)&whs[(d + 3) * 128 + j0];
            #pragma unroll
            for (int r = 0; r < 8; ++r) {
                const float4 av = *(const float4*)&ags[(r0 + r) * 64 + d];
                acc[r][0] = fmaf(av.x, wv0.x, acc[r][0]);
                acc[r][1] = fmaf(av.x, wv0.y, acc[r][1]);
                acc[r][2] = fmaf(av.x, wv0.z, acc[r][2]);
                acc[r][3] = fmaf(av.x, wv0.w, acc[r][3]);
                acc[r][0] = fmaf(av.y, wv1.x, acc[r][0]);
                acc[r][1] = fmaf(av.y, wv1.y, acc[r][1]);
                acc[r][2] = fmaf(av.y, wv1.z, acc[r][2]);
                acc[r][3] = fmaf(av.y, wv1.w, acc[r][3]);
                acc[r][0] = fmaf(av.z, wv2.x, acc[r][0]);
                acc[r][1] = fmaf(av.z, wv2.y, acc[r][1]);
                acc[r][2] = fmaf(av.z, wv2.z, acc[r][2]);
                acc[r][3] = fmaf(av.z, wv2.w, acc[r][3]);
                acc[r][0] = fmaf(av.w, wv3.x, acc[r][0]);
                acc[r][1] = fmaf(av.w, wv3.y, acc[r][1]);
                acc[r][2] = fmaf(av.w, wv3.z, acc[r][2]);
                acc[r][3] = fmaf(av.w, wv3.w, acc[r][3]);
            }
        }
        __syncthreads();
    }
    #pragma unroll
    for (int r = 0; r < 8; ++r) {
        const int row = rbase + r0 + r;
        if (row < nrows)
            *(float4*)&out[(long)row * 128 + j0] =
                make_float4(acc[r][0], acc[r][1], acc[r][2], acc[r][3]);
    }
}

extern "C" void kernel_launch(void* const* d_in, const int* in_sizes, int n_in,
                              void* d_out, int out_size, void* d_ws, size_t ws_size,
                              hipStream_t stream) {
    // inputs: 0 q_sub (unused), 1 q_rel, 2 hidden, 3 edges, 4 n_node,
    //         5 rela_embed, 6 Ws, 7 Wr, 8 Wqr, 9 bqr, 10 wa, 11 ba, 12 Wh
    const int*   q_rel  = (const int*)d_in[1];
    const float* hidden = (const float*)d_in[2];
    const int*   edges  = (const int*)d_in[3];
    const float* rela   = (const float*)d_in[5];
    const float* Ws     = (const float*)d_in[6];
    const float* Wr     = (const float*)d_in[7];
    const float* Wqr    = (const float*)d_in[8];
    const float* bqr    = (const float*)d_in[9];
    const float* wa     = (const float*)d_in[10];
    const float* ba     = (const float*)d_in[11];
    const float* Wh     = (const float*)d_in[12];

    const int B  = in_sizes[1];
    const int N  = in_sizes[2] / DD;
    const int E  = in_sizes[3] / 6;
    const int NR = in_sizes[5] / DD;

    float* out = (float*)d_out;

    float* hsWs   = (float*)d_ws;                    // N  x 64
    float* hrWr   = hsWs   + (size_t)N  * AA;        // NR x 64
    float* hqrWqr = hrWr   + (size_t)NR * AA;        // B  x 64
    int*   deg    = (int*)(hqrWqr + (size_t)B * AA); // N
    int*   cur    = deg  + N;                        // N
    int*   offs   = cur  + N;                        // N
    int*   bsum   = offs + N;                        // 64
    int*   bsumx  = bsum + 64;                       // 64
    int2*  recs   = (int2*)(bsumx + 64);             // E

    const int nb = idiv_up(N, 1024);

    hipMemsetAsync(deg, 0, (size_t)N * sizeof(int), stream);
    proj_gemm_kernel<<<idiv_up(N, 64), 256, 0, stream>>>(hidden, Ws, hsWs, N);
    rowmm_kernel<<<idiv_up(NR, 4), 256, 0, stream>>>(rela, Wr, nullptr, nullptr, hrWr, NR);
    rowmm_kernel<<<idiv_up(B, 4), 256, 0, stream>>>(rela, Wqr, bqr, q_rel, hqrWqr, B);
    hist_kernel<<<idiv_up(E, 256), 256, 0, stream>>>(edges, deg, E);
    scan1_kernel<<<nb, 256, 0, stream>>>(deg, offs, bsum, N);
    scan1_kernel<<<1, 256, 0, stream>>>(bsum, bsumx, nullptr, nb);
    scan_add_kernel<<<idiv_up(N, 256), 256, 0, stream>>>(offs, cur, bsumx, N);
    scatter_kernel<<<idiv_up(E, 256), 256, 0, stream>>>(edges, cur, recs, E);
    gather_kernel<<<idiv_up(N * 64, 256), 256, 0, stream>>>(recs, offs, hsWs, hrWr, hqrWqr,
                                                            hidden, rela, wa, ba, out, N, E);
    out_gemm_kernel<<<idiv_up(N, 64), 256, 0, stream>>>(out, Wh, out, N);
}

// Round 5
// 281.063 us; speedup vs baseline: 1.6161x; 1.0892x over previous
//
#include <hip/hip_runtime.h>

#define DD 128
#define AA 64

static inline int idiv_up(int a, int b) { return (a + b - 1) / b; }

__device__ __forceinline__ unsigned short f2bf(float f) {
    unsigned u = __float_as_uint(f);
    u += 0x7fff + ((u >> 16) & 1);          // round-to-nearest-even
    return (unsigned short)(u >> 16);
}
__device__ __forceinline__ float bf2f(unsigned short h) {
    return __uint_as_float(((unsigned)h) << 16);
}

// ---------------------------------------------------------------------------
// Fused projections. Block types:
//  A (nA blocks): hidden rows  -> hsWs16 (bf16, via Ws)  + hiddenWh (via Wh)
//  B (nB blocks): rela rows    -> hrWr   (f32, via Wr)   + relaWh   (via Wh)
//  C (nC blocks): rela[q_rel]  -> hqrWqr (f32, via Wqr, +bqr)
// Per block: stage 64-row source tile transposed in LDS once, then loop
// weight phases through a shared 32KB weight buffer.
// ---------------------------------------------------------------------------
__global__ __launch_bounds__(256)
void proj_all_kernel(const float* __restrict__ hidden,
                     const float* __restrict__ rela,
                     const int* __restrict__ q_rel,
                     const float* __restrict__ Ws,
                     const float* __restrict__ Wr,
                     const float* __restrict__ Wqr,
                     const float* __restrict__ bqr,
                     const float* __restrict__ Wh,
                     unsigned short* __restrict__ hsWs16,
                     float* __restrict__ hiddenWh,
                     float* __restrict__ hrWr,
                     float* __restrict__ relaWh,
                     float* __restrict__ hqrWqr,
                     int N, int NR, int B, int nA, int nB) {
    __shared__ float lht[128 * 64];    // transposed source tile [d][row]
    __shared__ float wbuf[128 * 64];   // current weight phase [d][c]
    const int t = threadIdx.x;
    const int bid = blockIdx.x;
    int type, rbase, nrows;
    const float* src;
    if (bid < nA)           { type = 0; rbase = bid * 64;             nrows = N;  src = hidden; }
    else if (bid < nA + nB) { type = 1; rbase = (bid - nA) * 64;      nrows = NR; src = rela; }
    else                    { type = 2; rbase = (bid - nA - nB) * 64; nrows = B;  src = rela; }

    // stage source tile (transposed)
    const int row = t & 63;
    const int d0 = (t >> 6) * 32;
    const int gr = rbase + row;
    const float* srow = nullptr;
    if (gr < nrows) {
        const int sr = (type == 2) ? q_rel[gr] : gr;
        srow = src + (long)sr * DD;
    }
    #pragma unroll
    for (int j = 0; j < 8; ++j) {
        float4 v = make_float4(0.f, 0.f, 0.f, 0.f);
        if (srow) v = *(const float4*)&srow[d0 + j * 4];
        lht[(d0 + j * 4 + 0) * 64 + row] = v.x;
        lht[(d0 + j * 4 + 1) * 64 + row] = v.y;
        lht[(d0 + j * 4 + 2) * 64 + row] = v.z;
        lht[(d0 + j * 4 + 3) * 64 + row] = v.w;
    }

    const int r0 = (t & 15) * 4;
    const int c0 = (t >> 4) * 4;
    const int nph = (type == 2) ? 1 : 3;

    for (int p = 0; p < nph; ++p) {
        const float* W;
        int ldw, off;
        if (p == 0) {
            W = (type == 0) ? Ws : (type == 1) ? Wr : Wqr;
            ldw = 64; off = 0;
        } else {
            W = Wh; ldw = 128; off = (p - 1) * 64;
        }
        #pragma unroll
        for (int k = 0; k < 8192; k += 1024) {
            const int f = k + t * 4;
            *(float4*)&wbuf[f] = *(const float4*)&W[(long)(f >> 6) * ldw + off + (f & 63)];
        }
        __syncthreads();

        float acc[4][4] = {};
        #pragma unroll 4
        for (int d = 0; d < 128; ++d) {
            const float4 hv = *(const float4*)&lht[d * 64 + r0];
            const float4 wv = *(const float4*)&wbuf[d * 64 + c0];
            acc[0][0] = fmaf(hv.x, wv.x, acc[0][0]);
            acc[0][1] = fmaf(hv.x, wv.y, acc[0][1]);
            acc[0][2] = fmaf(hv.x, wv.z, acc[0][2]);
            acc[0][3] = fmaf(hv.x, wv.w, acc[0][3]);
            acc[1][0] = fmaf(hv.y, wv.x, acc[1][0]);
            acc[1][1] = fmaf(hv.y, wv.y, acc[1][1]);
            acc[1][2] = fmaf(hv.y, wv.z, acc[1][2]);
            acc[1][3] = fmaf(hv.y, wv.w, acc[1][3]);
            acc[2][0] = fmaf(hv.z, wv.x, acc[2][0]);
            acc[2][1] = fmaf(hv.z, wv.y, acc[2][1]);
            acc[2][2] = fmaf(hv.z, wv.z, acc[2][2]);
            acc[2][3] = fmaf(hv.z, wv.w, acc[2][3]);
            acc[3][0] = fmaf(hv.w, wv.x, acc[3][0]);
            acc[3][1] = fmaf(hv.w, wv.y, acc[3][1]);
            acc[3][2] = fmaf(hv.w, wv.z, acc[3][2]);
            acc[3][3] = fmaf(hv.w, wv.w, acc[3][3]);
        }

        #pragma unroll
        for (int i = 0; i < 4; ++i) {
            const int orow = rbase + r0 + i;
            if (orow >= nrows) continue;
            if (type == 0) {
                if (p == 0) {
                    ushort4 o;
                    o.x = f2bf(acc[i][0]); o.y = f2bf(acc[i][1]);
                    o.z = f2bf(acc[i][2]); o.w = f2bf(acc[i][3]);
                    *(ushort4*)&hsWs16[(long)orow * 64 + c0] = o;
                } else {
                    *(float4*)&hiddenWh[(long)orow * 128 + off + c0] =
                        make_float4(acc[i][0], acc[i][1], acc[i][2], acc[i][3]);
                }
            } else if (type == 1) {
                if (p == 0) {
                    *(float4*)&hrWr[(long)orow * 64 + c0] =
                        make_float4(acc[i][0], acc[i][1], acc[i][2], acc[i][3]);
                } else {
                    *(float4*)&relaWh[(long)orow * 128 + off + c0] =
                        make_float4(acc[i][0], acc[i][1], acc[i][2], acc[i][3]);
                }
            } else {
                const float4 bq = *(const float4*)&bqr[c0];
                *(float4*)&hqrWqr[(long)orow * 64 + c0] =
                    make_float4(acc[i][0] + bq.x, acc[i][1] + bq.y,
                                acc[i][2] + bq.z, acc[i][3] + bq.w);
            }
        }
        __syncthreads();   // wbuf reused next phase
    }
}

// ---------- counting sort by obj (non-cooperative, proven in round 3) ----------
__global__ void hist_kernel(const int* __restrict__ edges, int* deg, int E) {
    const int e = blockIdx.x * blockDim.x + threadIdx.x;
    if (e < E) atomicAdd(&deg[edges[(long)e * 6 + 5]], 1);
}

__global__ void scan1_kernel(const int* __restrict__ in, int* __restrict__ out,
                             int* __restrict__ bsum, int n) {
    __shared__ int tsum[256];
    const int t = threadIdx.x;
    const int base = blockIdx.x * 1024 + t * 4;
    int v[4];
    int s = 0;
    #pragma unroll
    for (int j = 0; j < 4; ++j) {
        v[j] = (base + j < n) ? in[base + j] : 0;
        s += v[j];
    }
    tsum[t] = s;
    __syncthreads();
    for (int o = 1; o < 256; o <<= 1) {
        int x = (t >= o) ? tsum[t - o] : 0;
        __syncthreads();
        tsum[t] += x;
        __syncthreads();
    }
    int run = (t > 0) ? tsum[t - 1] : 0;
    if (t == 255 && bsum) bsum[blockIdx.x] = tsum[255];
    #pragma unroll
    for (int j = 0; j < 4; ++j) {
        if (base + j < n) out[base + j] = run;
        run += v[j];
    }
}

// offs += block prefix; also materialize cur = offs copy for the scatter atomics
__global__ void scan_add_kernel(int* offs, int* cur, const int* __restrict__ bsumx, int n) {
    const int i = blockIdx.x * blockDim.x + threadIdx.x;
    if (i < n) {
        const int v = offs[i] + bsumx[i >> 10];
        offs[i] = v;
        cur[i] = v;
    }
}

// pack (sub, rel | ridx<<16) records bucketed by obj; cur pre-seeded with offs
__global__ void scatter_kernel(const int* __restrict__ edges, int* cur,
                               int2* __restrict__ recs, int E) {
    const int e = blockIdx.x * blockDim.x + threadIdx.x;
    if (e >= E) return;
    const int* ed = edges + (long)e * 6;
    const int pos = atomicAdd(&cur[ed[5]], 1);
    recs[pos] = make_int2(ed[4], ed[2] | (ed[0] << 16));
}

// ---------------------------------------------------------------------------
// Gather: one wave per destination node, 16 lanes per edge (4 edges in flight).
// Writes the FINAL output row: out[v] = sum_e alpha_e * (hiddenWh[sub] + relaWh[rel])
// ---------------------------------------------------------------------------
__global__ __launch_bounds__(256)
void gather_kernel(const int2* __restrict__ recs,
                   const int* __restrict__ offs,
                   const unsigned short* __restrict__ hsWs16,
                   const float* __restrict__ hrWr,
                   const float* __restrict__ hqrWqr,
                   const float* __restrict__ hiddenWh,
                   const float* __restrict__ relaWh,
                   const float* __restrict__ wa,
                   const float* __restrict__ ba,
                   float* __restrict__ out, int N, int E) {
    const int lane = threadIdx.x & 63;
    const int g = lane >> 4;      // edge-group 0..3
    const int l = lane & 15;      // lane within group
    const int v = (int)((blockIdx.x * blockDim.x + threadIdx.x) >> 6);
    if (v >= N) return;
    const float4 wav = *(const float4*)&wa[l * 4];
    const float bar = ba[0];
    const int start = offs[v];
    const int end = (v + 1 < N) ? offs[v + 1] : E;

    float4 acc0 = make_float4(0.f, 0.f, 0.f, 0.f);
    float4 acc1 = make_float4(0.f, 0.f, 0.f, 0.f);

    for (int base = start; base < end; base += 4) {
        const int k = base + g;
        const bool valid = (k < end);
        const int2 rec = valid ? recs[k] : make_int2(0, 0);
        const int sub  = rec.x;
        const int rel  = rec.y & 0xffff;
        const int ridx = rec.y >> 16;

        // logit: 4 features per lane, 16 lanes per edge
        const ushort4 hw = *(const ushort4*)&hsWs16[(long)sub * AA + l * 4];
        const float4 b4 = *(const float4*)&hrWr[rel * AA + l * 4];
        const float4 c4 = *(const float4*)&hqrWqr[ridx * AA + l * 4];
        float s = fmaxf(bf2f(hw.x) + b4.x + c4.x, 0.f) * wav.x;
        s = fmaf(fmaxf(bf2f(hw.y) + b4.y + c4.y, 0.f), wav.y, s);
        s = fmaf(fmaxf(bf2f(hw.z) + b4.z + c4.z, 0.f), wav.z, s);
        s = fmaf(fmaxf(bf2f(hw.w) + b4.w + c4.w, 0.f), wav.w, s);
        s += __shfl_xor(s, 1);
        s += __shfl_xor(s, 2);
        s += __shfl_xor(s, 4);
        s += __shfl_xor(s, 8);
        float alpha = __builtin_amdgcn_rcpf(1.0f + __expf(-(s + bar)));
        if (!valid) alpha = 0.0f;

        // message (already through Wh): 8 features per lane
        const float4 h0 = *(const float4*)&hiddenWh[(long)sub * DD + l * 8];
        const float4 h1 = *(const float4*)&hiddenWh[(long)sub * DD + l * 8 + 4];
        const float4 r0 = *(const float4*)&relaWh[rel * DD + l * 8];
        const float4 r1 = *(const float4*)&relaWh[rel * DD + l * 8 + 4];
        acc0.x = fmaf(alpha, h0.x + r0.x, acc0.x);
        acc0.y = fmaf(alpha, h0.y + r0.y, acc0.y);
        acc0.z = fmaf(alpha, h0.z + r0.z, acc0.z);
        acc0.w = fmaf(alpha, h0.w + r0.w, acc0.w);
        acc1.x = fmaf(alpha, h1.x + r1.x, acc1.x);
        acc1.y = fmaf(alpha, h1.y + r1.y, acc1.y);
        acc1.z = fmaf(alpha, h1.z + r1.z, acc1.z);
        acc1.w = fmaf(alpha, h1.w + r1.w, acc1.w);
    }

    // combine the 4 edge-groups
    #pragma unroll
    for (int o = 16; o <= 32; o <<= 1) {
        acc0.x += __shfl_xor(acc0.x, o);
        acc0.y += __shfl_xor(acc0.y, o);
        acc0.z += __shfl_xor(acc0.z, o);
        acc0.w += __shfl_xor(acc0.w, o);
        acc1.x += __shfl_xor(acc1.x, o);
        acc1.y += __shfl_xor(acc1.y, o);
        acc1.z += __shfl_xor(acc1.z, o);
        acc1.w += __shfl_xor(acc1.w, o);
    }
    if (g == 0) {
        *(float4*)&out[(long)v * DD + l * 8]     = acc0;
        *(float4*)&out[(long)v * DD + l * 8 + 4] = acc1;
    }
}

extern "C" void kernel_launch(void* const* d_in, const int* in_sizes, int n_in,
                              void* d_out, int out_size, void* d_ws, size_t ws_size,
                              hipStream_t stream) {
    // inputs: 0 q_sub (unused), 1 q_rel, 2 hidden, 3 edges, 4 n_node,
    //         5 rela_embed, 6 Ws, 7 Wr, 8 Wqr, 9 bqr, 10 wa, 11 ba, 12 Wh
    const int*   q_rel  = (const int*)d_in[1];
    const float* hidden = (const float*)d_in[2];
    const int*   edges  = (const int*)d_in[3];
    const float* rela   = (const float*)d_in[5];
    const float* Ws     = (const float*)d_in[6];
    const float* Wr     = (const float*)d_in[7];
    const float* Wqr    = (const float*)d_in[8];
    const float* bqr    = (const float*)d_in[9];
    const float* wa     = (const float*)d_in[10];
    const float* ba     = (const float*)d_in[11];
    const float* Wh     = (const float*)d_in[12];

    const int B  = in_sizes[1];
    const int N  = in_sizes[2] / DD;
    const int E  = in_sizes[3] / 6;
    const int NR = in_sizes[5] / DD;

    float* out = (float*)d_out;

    // workspace layout
    unsigned short* hsWs16 = (unsigned short*)d_ws;               // N x 64 bf16
    float* hiddenWh = (float*)(hsWs16 + (size_t)N * AA);          // N x 128 f32
    float* hrWr     = hiddenWh + (size_t)N * DD;                  // NR x 64
    float* relaWh   = hrWr + (size_t)NR * AA;                     // NR x 128
    float* hqrWqr   = relaWh + (size_t)NR * DD;                   // B x 64
    int*   deg      = (int*)(hqrWqr + (size_t)B * AA);            // N
    int*   cur      = deg  + N;                                   // N
    int*   offs     = cur  + N;                                   // N
    int*   bsum     = offs + N;                                   // 64
    int*   bsumx    = bsum + 64;                                  // 64
    int2*  recs     = (int2*)(bsumx + 64);                        // E

    const int nA = idiv_up(N, 64);
    const int nB = idiv_up(NR, 64);
    const int nC = idiv_up(B, 64);
    const int nb = idiv_up(N, 1024);

    hipMemsetAsync(deg, 0, (size_t)N * sizeof(int), stream);
    proj_all_kernel<<<nA + nB + nC, 256, 0, stream>>>(
        hidden, rela, q_rel, Ws, Wr, Wqr, bqr, Wh,
        hsWs16, hiddenWh, hrWr, relaWh, hqrWqr, N, NR, B, nA, nB);
    hist_kernel<<<idiv_up(E, 256), 256, 0, stream>>>(edges, deg, E);
    scan1_kernel<<<nb, 256, 0, stream>>>(deg, offs, bsum, N);
    scan1_kernel<<<1, 256, 0, stream>>>(bsum, bsumx, nullptr, nb);
    scan_add_kernel<<<idiv_up(N, 256), 256, 0, stream>>>(offs, cur, bsumx, N);
    scatter_kernel<<<idiv_up(E, 256), 256, 0, stream>>>(edges, cur, recs, E);
    gather_kernel<<<idiv_up(N * 64, 256), 256, 0, stream>>>(
        recs, offs, hsWs16, hrWr, hqrWqr, hiddenWh, relaWh, wa, ba, out, N, E);
}